// Round 10
// baseline (3433.483 us; speedup 1.0000x reference)
//
#include <hip/hip_runtime.h>
#include <math.h>

#define K_PATCHES 25
#define GRID_SIDE 20
#define G_PTS     400
#define LATENT    1024
#define BATCH     16

typedef _Float16 f16x8 __attribute__((ext_vector_type(8)));
typedef float    f32x4 __attribute__((ext_vector_type(4)));

// publish LDS writes to the block WITHOUT draining vmcnt
#define LGKM_BAR() do {                                      \
    asm volatile("s_waitcnt lgkmcnt(0)" ::: "memory");       \
    __builtin_amdgcn_sched_barrier(0);                       \
    __builtin_amdgcn_s_barrier();                            \
    __builtin_amdgcn_sched_barrier(0);                       \
} while (0)

// ws layout (bytes)
#define BASE_OFF 0                      // 16*25*1024 f32 = 1,638,400
#define WT2_OFF  1638400                // 25*512*1024 f16 = 26,214,400
#define WT3_OFF  27852800               // 25*256*512 f16  =  6,553,600
#define WT4_OFF  34406400               // 25*128*256 f16  =  1,638,400
#define H2WS_OFF 36044800               // 1250 tiles * 128*512 f16 = 163,840,000

// ---------------------------------------------------------------------------
// Kernel 1: base[b][p][o] = b1[p][o] + sum_k x[b][k]*W1[p][k][o]  (o<1024)
// ---------------------------------------------------------------------------
__global__ __launch_bounds__(128)
void base_kernel(const float* __restrict__ x,
                 const float* __restrict__ W1,
                 const float* __restrict__ b1,
                 float* __restrict__ base) {
    __shared__ float xs[BATCH][LATENT];   // 64 KB
    const int p  = blockIdx.x >> 3;
    const int oc = blockIdx.x & 7;
    const int o  = oc * 128 + threadIdx.x;

    for (int idx = threadIdx.x; idx < BATCH * LATENT / 4; idx += 128)
        ((float4*)xs)[idx] = ((const float4*)x)[idx];
    __syncthreads();

    float acc[BATCH];
#pragma unroll
    for (int b = 0; b < BATCH; ++b) acc[b] = 0.0f;

    const float* Wp = W1 + (size_t)p * 1026 * 1024 + o;
    for (int k = 0; k < LATENT; k += 4) {
        const float w0 = Wp[(size_t)(k + 0) * 1024];
        const float w1 = Wp[(size_t)(k + 1) * 1024];
        const float w2 = Wp[(size_t)(k + 2) * 1024];
        const float w3 = Wp[(size_t)(k + 3) * 1024];
#pragma unroll
        for (int b = 0; b < BATCH; ++b) {
            const float4 xv = *(const float4*)&xs[b][k];
            acc[b] = fmaf(xv.w, w3, fmaf(xv.z, w2, fmaf(xv.y, w1, fmaf(xv.x, w0, acc[b]))));
        }
    }

    const float bias = b1[p * 1024 + o];
    for (int b = 0; b < BATCH; ++b)
        base[(size_t)(b * K_PATCHES + p) * 1024 + o] = acc[b] + bias;
}

// ---------------------------------------------------------------------------
// One-shot transpose + fp16 convert for W2/W3/W4: W[p][K][N] -> Wt[p][N][K]
// ---------------------------------------------------------------------------
__global__ __launch_bounds__(256)
void conv_tr_all(const float* __restrict__ W2, _Float16* __restrict__ Wt2,
                 const float* __restrict__ W3, _Float16* __restrict__ Wt3,
                 const float* __restrict__ W4, _Float16* __restrict__ Wt4) {
    __shared__ float tile[64][65];
    int bb = blockIdx.x;
    const float* W; _Float16* Wt; int K, N, rel;
    if (bb < 3200)      { W = W2; Wt = Wt2; K = 1024; N = 512; rel = bb; }
    else if (bb < 4000) { W = W3; Wt = Wt3; K = 512;  N = 256; rel = bb - 3200; }
    else                { W = W4; Wt = Wt4; K = 256;  N = 128; rel = bb - 4000; }

    const int tpp = (K / 64) * (N / 64);
    const int p   = rel / tpp;
    const int rem = rel % tpp;
    const int kt  = rem / (N / 64);
    const int nt  = rem % (N / 64);
    const int tr  = threadIdx.x >> 6;
    const int tc  = threadIdx.x & 63;

    const float* Wp = W + ((size_t)p * K + kt * 64) * N + nt * 64;
#pragma unroll
    for (int i = 0; i < 64; i += 4)
        tile[i + tr][tc] = Wp[(size_t)(i + tr) * N + tc];
    __syncthreads();

    _Float16* Wtp = Wt + ((size_t)p * N + nt * 64) * K + kt * 64;
#pragma unroll
    for (int i = 0; i < 64; i += 4)
        Wtp[(size_t)(i + tr) * K + tc] = (_Float16)tile[tc][i + tr];
}

// ---------------------------------------------------------------------------
// XCD-swizzled tile mapping: 1250 tiles, bijective over 8 XCDs
// ---------------------------------------------------------------------------
__device__ __forceinline__ int tile_ord1250(int bid) {
    const int xcd = bid & 7;
    const int ii  = bid >> 3;
    return (xcd < 2) ? xcd * 157 + ii : 2 * 157 + (xcd - 2) * 156 + ii;
}

// ---------------------------------------------------------------------------
// K_A: layers 1+2 for a 128-row x FULL-512-col tile (1250 blocks).
// KC=64: 64 MFMAs per barrier per wave (4x R9's work-per-barrier); h1
// produced exactly once per row-tile. 8 waves = 2M x 4N, wave 64M x 128N.
// h2 -> global canonical [64 ko][128 r][8 f16].
// ---------------------------------------------------------------------------
__global__
void gemm_l12(const float* __restrict__ base,
              const float* __restrict__ W1,
              const _Float16* __restrict__ Wt2, const float* __restrict__ b2,
              _Float16* __restrict__ h2g) {
    __shared__ __align__(16) unsigned char LDS[49152];
    constexpr int OFF_SB = 0;        // 2 x 4KB base rows f32
    constexpr int OFF_WU = 8192;     // 4KB
    constexpr int OFF_WV = 12288;    // 4KB
    constexpr int OFF_H1 = 16384;    // 2 x 16KB [8 kq][128 r][8 f16]

    const int ord   = tile_ord1250(blockIdx.x);
    const int p     = ord / 50;
    const int mt    = ord % 50;
    const int rbase = mt * 128;

    const int t    = threadIdx.x;
    const int lane = t & 63;
    const int w    = t >> 6;
    const int wm   = w >> 2;           // 0..1  (64-row half)
    const int wn   = w & 3;            // 0..3  (128-col slice)
    const int l16  = lane & 15;
    const int lq   = lane >> 4;

    float* sb0  = (float*)(LDS + OFF_SB);
    float* sb1  = sb0 + 1024;
    float* swuf = (float*)(LDS + OFF_WU);
    float* swvf = (float*)(LDS + OFF_WV);

    const int b0i = rbase / 400;
    const int b1i = (rbase + 127) / 400;
    {
        const float* base0 = base + (size_t)(b0i * K_PATCHES + p) * 1024;
        const float* base1 = base + (size_t)(b1i * K_PATCHES + p) * 1024;
        const float* wup   = W1 + (size_t)p * 1026 * 1024 + (size_t)1024 * 1024;
        if (t < 256) ((float4*)sb0)[t] = ((const float4*)base0)[t];
        else         ((float4*)sb1)[t - 256] = ((const float4*)base1)[t - 256];
        if (t < 256) ((float4*)swuf)[t] = ((const float4*)wup)[t];
        else         ((float4*)swvf)[t - 256] = ((const float4*)(wup + 1024))[t - 256];
    }
    __syncthreads();

    // h1 producer: thread t -> row pr (0..127), octet-pair ph (0..3).
    // Produces k-octets kq=ph (k=kc+ph*8) and kq=ph+4 (k=kc+32+ph*8).
    const int pr = t & 127;
    const int ph = t >> 7;
    const float* sbm2 = (rbase + pr < (b0i + 1) * 400) ? sb0 : sb1;
    const int pg  = (rbase + pr) % 400;
    const float pu = (float)(pg % GRID_SIDE) * (1.0f / 19.0f);
    const float pv = (float)(pg / GRID_SIDE) * (1.0f / 19.0f);

    auto produceOct = [&](int k, unsigned char* dst, unsigned off) {
        const float4 bv0 = *(const float4*)&sbm2[k];
        const float4 bv1 = *(const float4*)&sbm2[k + 4];
        const float4 u0  = *(const float4*)&swuf[k];
        const float4 u1  = *(const float4*)&swuf[k + 4];
        const float4 v0  = *(const float4*)&swvf[k];
        const float4 v1  = *(const float4*)&swvf[k + 4];
        f16x8 hv;
        hv[0] = (_Float16)fmaxf(fmaf(pv, v0.x, fmaf(pu, u0.x, bv0.x)), 0.0f);
        hv[1] = (_Float16)fmaxf(fmaf(pv, v0.y, fmaf(pu, u0.y, bv0.y)), 0.0f);
        hv[2] = (_Float16)fmaxf(fmaf(pv, v0.z, fmaf(pu, u0.z, bv0.z)), 0.0f);
        hv[3] = (_Float16)fmaxf(fmaf(pv, v0.w, fmaf(pu, u0.w, bv0.w)), 0.0f);
        hv[4] = (_Float16)fmaxf(fmaf(pv, v1.x, fmaf(pu, u1.x, bv1.x)), 0.0f);
        hv[5] = (_Float16)fmaxf(fmaf(pv, v1.y, fmaf(pu, u1.y, bv1.y)), 0.0f);
        hv[6] = (_Float16)fmaxf(fmaf(pv, v1.z, fmaf(pu, u1.z, bv1.z)), 0.0f);
        hv[7] = (_Float16)fmaxf(fmaf(pv, v1.w, fmaf(pu, u1.w, bv1.w)), 0.0f);
        *(f16x8*)(dst + off) = hv;
    };
    auto produce2 = [&](int kc, unsigned char* dst) {
        produceOct(kc + ph * 8,      dst, (unsigned)((ph * 128 + pr) * 16));
        produceOct(kc + 32 + ph * 8, dst, (unsigned)(((ph + 4) * 128 + pr) * 16));
    };

    const _Float16* Wt2p = Wt2 + (size_t)p * 512 * 1024;
    const _Float16* b2base = Wt2p + (size_t)(wn * 128 + l16) * 1024 + lq * 8;

    f32x4 acc2[4][8];
    {
        const float* b2p = b2 + p * 512;
#pragma unroll
        for (int nf = 0; nf < 8; ++nf) {
            const float bias = b2p[wn * 128 + nf * 16 + l16];
            f32x4 bv = {bias, bias, bias, bias};
#pragma unroll
            for (int mf = 0; mf < 4; ++mf) acc2[mf][nf] = bv;
        }
    }

    f16x8 b0[8], b1[8];
    auto loadB = [&](int kc) {
#pragma unroll
        for (int nf = 0; nf < 8; ++nf) {
            b0[nf] = *(const f16x8*)(b2base + (size_t)nf * 16384 + kc);
            b1[nf] = *(const f16x8*)(b2base + (size_t)nf * 16384 + kc + 32);
        }
    };

    // prologue: h1 chunk0 + B chunk0
    produce2(0, LDS + OFF_H1);
    loadB(0);
    __syncthreads();

#pragma unroll 1
    for (int c = 0; c < 16; ++c) {
        unsigned char* h1cur = LDS + OFF_H1 + (c & 1) * 16384;
        if (c + 1 < 16)
            produce2((c + 1) * 64, LDS + OFF_H1 + ((c + 1) & 1) * 16384);
        // ks = 0
        {
            f16x8 a[4];
#pragma unroll
            for (int mf = 0; mf < 4; ++mf)
                a[mf] = *(const f16x8*)(h1cur + ((lq) * 128 + wm * 64 + mf * 16 + l16) * 16);
            __builtin_amdgcn_s_setprio(1);
#pragma unroll
            for (int mf = 0; mf < 4; ++mf)
#pragma unroll
                for (int nf = 0; nf < 8; ++nf)
                    acc2[mf][nf] = __builtin_amdgcn_mfma_f32_16x16x32_f16(a[mf], b0[nf], acc2[mf][nf], 0, 0, 0);
            __builtin_amdgcn_s_setprio(0);
        }
        // ks = 1
        {
            f16x8 a[4];
#pragma unroll
            for (int mf = 0; mf < 4; ++mf)
                a[mf] = *(const f16x8*)(h1cur + ((4 + lq) * 128 + wm * 64 + mf * 16 + l16) * 16);
            __builtin_amdgcn_s_setprio(1);
#pragma unroll
            for (int mf = 0; mf < 4; ++mf)
#pragma unroll
                for (int nf = 0; nf < 8; ++nf)
                    acc2[mf][nf] = __builtin_amdgcn_mfma_f32_16x16x32_f16(a[mf], b1[nf], acc2[mf][nf], 0, 0, 0);
            __builtin_amdgcn_s_setprio(0);
        }
        if (c + 1 < 16)
            loadB((c + 1) * 64);   // issued after use; covered by barrier+produce+A-reads
        LGKM_BAR();                // publish h1; global B loads stay in flight
    }

    // h2 = relu(acc2) -> global canonical [64 ko][128 r][8]
    _Float16* hp = h2g + (size_t)ord * 128 * 512;
#pragma unroll
    for (int mf = 0; mf < 4; ++mf)
#pragma unroll
        for (int nf = 0; nf < 8; ++nf)
#pragma unroll
            for (int r = 0; r < 4; ++r) {
                const int row = wm * 64 + mf * 16 + lq * 4 + r;
                const int col = wn * 128 + nf * 16 + l16;
                hp[(size_t)(col >> 3) * 1024 + row * 8 + (col & 7)] =
                    (_Float16)fmaxf(acc2[mf][nf][r], 0.0f);
            }
}

// ---------------------------------------------------------------------------
// K_B: layers 3+4+5 for a 128-row tile (1250 blocks). A from canonical h2,
// depth-4 prefetch (L3/HBM latency cover); B3 depth-2 (L2-hot); h3/h4 in LDS.
// ---------------------------------------------------------------------------
__global__
void gemm_l345(const _Float16* __restrict__ h2g,
               const _Float16* __restrict__ Wt3, const float* __restrict__ b3,
               const _Float16* __restrict__ Wt4, const float* __restrict__ b4,
               const float* __restrict__ W5, const float* __restrict__ b5,
               float* __restrict__ out) {
    __shared__ __align__(16) unsigned char LDS[98304];
    constexpr int OFF_H3 = 0;        // 64KB [32 ko][128 r][8 f16]
    constexpr int OFF_H4 = 65536;    // 32KB [16 ko][128 r][8 f16]

    const int ord   = tile_ord1250(blockIdx.x);
    const int p     = ord / 50;
    const int mt    = ord % 50;
    const int rbase = mt * 128;

    const int t    = threadIdx.x;
    const int lane = t & 63;
    const int w    = t >> 6;
    const int wm   = w >> 2;           // 0..1
    const int wn   = w & 3;            // 0..3
    const int l16  = lane & 15;
    const int lq   = lane >> 4;

    const _Float16* hp = h2g + (size_t)ord * 128 * 512;   // [64 ko][128 r][8]

    // =======================  Layer 3: 128x256, K=512  ======================
    const _Float16* Wt3p = Wt3 + (size_t)p * 256 * 512;
    const _Float16* b3base = Wt3p + (size_t)(wn * 64 + l16) * 512 + lq * 8;
    f32x4 acc3[4][4];
    {
        const float* b3p = b3 + p * 256;
#pragma unroll
        for (int nf = 0; nf < 4; ++nf) {
            const float bias = b3p[wn * 64 + nf * 16 + l16];
            f32x4 bv = {bias, bias, bias, bias};
#pragma unroll
            for (int mf = 0; mf < 4; ++mf) acc3[mf][nf] = bv;
        }
    }
    const _Float16* a3base = hp + (size_t)(lq * 128 + wm * 64 + l16) * 8;

    auto loadA = [&](f16x8 (&dst)[4], int cc) {
#pragma unroll
        for (int mf = 0; mf < 4; ++mf)
            dst[mf] = *(const f16x8*)(a3base + (size_t)(cc * 4 * 1024 + mf * 128));
    };
    auto loadB3 = [&](f16x8 (&dst)[4], int cc) {
#pragma unroll
        for (int nf = 0; nf < 4; ++nf)
            dst[nf] = *(const f16x8*)(b3base + (size_t)nf * 8192 + cc * 32);
    };

    f16x8 aP[4], aQ[4], aR[4], aS[4], bX[4], bY[4];
    loadA(aP, 0); loadA(aQ, 1); loadA(aR, 2); loadA(aS, 3);
    loadB3(bX, 0); loadB3(bY, 1);

    auto l3s = [&](int cc, f16x8 (&ac)[4], f16x8 (&bc)[4]) {
        __builtin_amdgcn_s_setprio(1);
#pragma unroll
        for (int mf = 0; mf < 4; ++mf)
#pragma unroll
            for (int nf = 0; nf < 4; ++nf)
                acc3[mf][nf] = __builtin_amdgcn_mfma_f32_16x16x32_f16(ac[mf], bc[nf], acc3[mf][nf], 0, 0, 0);
        __builtin_amdgcn_s_setprio(0);
        if (cc + 2 < 16) loadB3(bc, cc + 2);
        if (cc + 4 < 16) loadA(ac, cc + 4);
    };

#pragma unroll 1
    for (int cc = 0; cc < 16; cc += 4) {
        l3s(cc + 0, aP, bX);
        l3s(cc + 1, aQ, bY);
        l3s(cc + 2, aR, bX);
        l3s(cc + 3, aS, bY);
    }

    // store h3 canonical [32 ko][128 r][8]
#pragma unroll
    for (int mf = 0; mf < 4; ++mf)
#pragma unroll
        for (int nf = 0; nf < 4; ++nf)
#pragma unroll
            for (int r = 0; r < 4; ++r) {
                const int row = wm * 64 + mf * 16 + lq * 4 + r;
                const int col = wn * 64 + nf * 16 + l16;
                const float v = fmaxf(acc3[mf][nf][r], 0.0f);
                *(_Float16*)(LDS + OFF_H3 + ((col >> 3) * 128 + row) * 16 + (col & 7) * 2) = (_Float16)v;
            }
    LGKM_BAR();

    // =======================  Layer 4: 128x128, K=256  ======================
    const _Float16* Wt4p = Wt4 + (size_t)p * 128 * 256;
    const _Float16* b4base = Wt4p + (size_t)(w * 16 + l16) * 256 + lq * 8;
    f16x8 dreg[8];
#pragma unroll
    for (int c = 0; c < 8; ++c)
        dreg[c] = *(const f16x8*)(b4base + c * 32);

#pragma unroll 1
    for (int half = 0; half < 2; ++half) {
        f32x4 acc4[4];
        {
            const float* b4p = b4 + p * 128;
            const float bias = b4p[w * 16 + l16];
            f32x4 bv = {bias, bias, bias, bias};
#pragma unroll
            for (int mf = 0; mf < 4; ++mf) acc4[mf] = bv;
        }
#pragma unroll
        for (int c = 0; c < 8; ++c) {
            f16x8 a[4];
#pragma unroll
            for (int mf = 0; mf < 4; ++mf)
                a[mf] = *(const f16x8*)(LDS + OFF_H3 +
                         ((c * 4 + lq) * 128 + half * 64 + mf * 16 + l16) * 16);
            __builtin_amdgcn_s_setprio(1);
#pragma unroll
            for (int mf = 0; mf < 4; ++mf)
                acc4[mf] = __builtin_amdgcn_mfma_f32_16x16x32_f16(a[mf], dreg[c], acc4[mf], 0, 0, 0);
            __builtin_amdgcn_s_setprio(0);
        }
#pragma unroll
        for (int mf = 0; mf < 4; ++mf)
#pragma unroll
            for (int r = 0; r < 4; ++r) {
                const int row = half * 64 + mf * 16 + lq * 4 + r;
                const int col = w * 16 + l16;
                const float v = fmaxf(acc4[mf][r], 0.0f);
                *(_Float16*)(LDS + OFF_H4 + ((col >> 3) * 128 + row) * 16 + (col & 7) * 2) = (_Float16)v;
            }
    }
    LGKM_BAR();

    // =======================  Layer 5: 128x3, K=128, tanh  ==================
    if (t < 384) {
        const int m = t / 3;
        const int c = t % 3;
        const float* W5p = W5 + p * 128 * 3;
        float acc = b5[p * 3 + c];
#pragma unroll 4
        for (int k = 0; k < 128; ++k) {
            const _Float16 hv = *(const _Float16*)(LDS + OFF_H4 + ((k >> 3) * 128 + m) * 16 + (k & 7) * 2);
            acc = fmaf((float)hv, W5p[k * 3 + c], acc);
        }
        const int r  = rbase + m;
        const int bb = r / 400;
        const int gg = r % 400;
        out[((size_t)(bb * K_PATCHES + p) * G_PTS + gg) * 3 + c] = tanhf(acc);
    }
}

extern "C" void kernel_launch(void* const* d_in, const int* in_sizes, int n_in,
                              void* d_out, int out_size, void* d_ws, size_t ws_size,
                              hipStream_t stream) {
    const float* x  = (const float*)d_in[0];
    const float* W1 = (const float*)d_in[1];
    const float* b1 = (const float*)d_in[2];
    const float* W2 = (const float*)d_in[3];
    const float* b2 = (const float*)d_in[4];
    const float* W3 = (const float*)d_in[5];
    const float* b3 = (const float*)d_in[6];
    const float* W4 = (const float*)d_in[7];
    const float* b4 = (const float*)d_in[8];
    const float* W5 = (const float*)d_in[9];
    const float* b5 = (const float*)d_in[10];
    float* out = (float*)d_out;

    float*     base = (float*)((char*)d_ws + BASE_OFF);
    _Float16*  Wt2  = (_Float16*)((char*)d_ws + WT2_OFF);
    _Float16*  Wt3  = (_Float16*)((char*)d_ws + WT3_OFF);
    _Float16*  Wt4  = (_Float16*)((char*)d_ws + WT4_OFF);
    _Float16*  h2g  = (_Float16*)((char*)d_ws + H2WS_OFF);

    base_kernel<<<K_PATCHES * 8, 128, 0, stream>>>(x, W1, b1, base);
    conv_tr_all<<<4200, 256, 0, stream>>>(W2, Wt2, W3, Wt3, W4, Wt4);

    gemm_l12<<<K_PATCHES * 50, 512, 0, stream>>>(base, W1, Wt2, b2, h2g);
    gemm_l345<<<K_PATCHES * 50, 512, 0, stream>>>(h2g, Wt3, b3, Wt4, b4, W5, b5, out);
}